// Round 1
// baseline (11246.252 us; speedup 1.0000x reference)
//
#include <hip/hip_runtime.h>

#define NE      16384
#define CIN     32
#define COUT    32
#define INDIM   16
#define FREQ    44
#define EDGEDIM 16
#define MID     32
#define KTOT    (CIN * FREQ)   // 1408

// ---------------------------------------------------------------------------
// Kernel 1: radial MLP -> h[E,32]  (Linear->LN->ReLU->Linear->LN->ReLU)
// block = 256 threads = 8 edges x 32 lanes (lane = m)
// ---------------------------------------------------------------------------
__global__ __launch_bounds__(256) void radial_h_kernel(
    const float* __restrict__ ef,
    const float* __restrict__ w1, const float* __restrict__ b1,
    const float* __restrict__ g1, const float* __restrict__ be1,
    const float* __restrict__ w2, const float* __restrict__ b2,
    const float* __restrict__ g2, const float* __restrict__ be2,
    float* __restrict__ h_out)
{
    const int tid = threadIdx.x;
    const int e = blockIdx.x * 8 + (tid >> 5);
    const int m = tid & 31;

    // load x[16] (broadcast across the 32 lanes of this edge)
    float xv[16];
    {
        const float4* xg = reinterpret_cast<const float4*>(ef + (size_t)e * EDGEDIM);
        #pragma unroll
        for (int i = 0; i < 4; i++) {
            float4 v = xg[i];
            xv[4*i+0] = v.x; xv[4*i+1] = v.y; xv[4*i+2] = v.z; xv[4*i+3] = v.w;
        }
    }
    // z1 = b1[m] + dot(x, w1[m,:])
    float z1 = b1[m];
    {
        float wv[16];
        const float4* wg = reinterpret_cast<const float4*>(w1 + (size_t)m * EDGEDIM);
        #pragma unroll
        for (int i = 0; i < 4; i++) {
            float4 v = wg[i];
            wv[4*i+0] = v.x; wv[4*i+1] = v.y; wv[4*i+2] = v.z; wv[4*i+3] = v.w;
        }
        #pragma unroll
        for (int j = 0; j < 16; j++) z1 += xv[j] * wv[j];
    }
    // LayerNorm over the 32 lanes (width-32 shuffle reduction)
    float s = z1, sq = z1 * z1;
    #pragma unroll
    for (int off = 1; off < 32; off <<= 1) {
        s  += __shfl_xor(s,  off, 32);
        sq += __shfl_xor(sq, off, 32);
    }
    float mu  = s  * (1.0f / 32.0f);
    float var = sq * (1.0f / 32.0f) - mu * mu;
    float h1 = (z1 - mu) * rsqrtf(var + 1e-5f) * g1[m] + be1[m];
    h1 = fmaxf(h1, 0.0f);

    // z2 = b2[m] + dot(h1_vec, w2[m,:]) via shuffle broadcast
    float z2 = b2[m];
    {
        float wv[32];
        const float4* wg = reinterpret_cast<const float4*>(w2 + (size_t)m * MID);
        #pragma unroll
        for (int i = 0; i < 8; i++) {
            float4 v = wg[i];
            wv[4*i+0] = v.x; wv[4*i+1] = v.y; wv[4*i+2] = v.z; wv[4*i+3] = v.w;
        }
        #pragma unroll
        for (int mp = 0; mp < 32; mp++) {
            float hv = __shfl(h1, mp, 32);
            z2 += hv * wv[mp];
        }
    }
    float s2 = z2, sq2 = z2 * z2;
    #pragma unroll
    for (int off = 1; off < 32; off <<= 1) {
        s2  += __shfl_xor(s2,  off, 32);
        sq2 += __shfl_xor(sq2, off, 32);
    }
    float mu2  = s2  * (1.0f / 32.0f);
    float var2 = sq2 * (1.0f / 32.0f) - mu2 * mu2;
    float h2 = (z2 - mu2) * rsqrtf(var2 + 1e-5f) * g2[m] + be2[m];
    h2 = fmaxf(h2, 0.0f);

    h_out[(size_t)e * MID + m] = h2;
}

// ---------------------------------------------------------------------------
// Kernel 2: fused  tmp = feat @ basis ;  radial = w3 @ h ;  out = radial @ tmp
// workgroup = 16 edges, 512 threads. Loop over f (44 chunks of k):
//   stage A: basis slab [16e][16j][16s] -> LDS   (basis read exactly once)
//   stage B: tmp slab   [16e][32ci][16s] -> LDS
//   stage C: thread (e,co): radial on the fly from w3 rows, accumulate out
// ---------------------------------------------------------------------------
__global__ __launch_bounds__(512, 2) void conv_main(
    const float* __restrict__ feat,    // [E,32,16]
    const float* __restrict__ basis,   // [E,16,44,16]
    const float* __restrict__ w3,      // [45056,32]
    const float* __restrict__ h_g,     // [E,32]
    float* __restrict__ out)           // [E,32,16]
{
    __shared__ __align__(16) float basis_s[16][16][16];  // 16 KB [e][j][s]
    __shared__ __align__(16) float tmp_s[16][32][16];    // 32 KB [e][ci][s]

    const int t  = threadIdx.x;
    const int e0 = blockIdx.x * 16;

    // stage-C identity
    const int ce = t >> 5;    // 0..15 edge
    const int co = t & 31;    // 0..31 output channel

    // preload h for this thread's edge into registers (reused for all f, ci)
    float hreg[32];
    {
        const float4* hg = reinterpret_cast<const float4*>(h_g + ((size_t)(e0 + ce)) * MID);
        #pragma unroll
        for (int i = 0; i < 8; i++) {
            float4 v = hg[i];
            hreg[4*i+0] = v.x; hreg[4*i+1] = v.y; hreg[4*i+2] = v.z; hreg[4*i+3] = v.w;
        }
    }
    float acc[16];
    #pragma unroll
    for (int s = 0; s < 16; s++) acc[s] = 0.0f;

    // stage-B identity
    const int bci = t >> 4;   // 0..31
    const int bs  = t & 15;   // 0..15

    const float4* basis4 = reinterpret_cast<const float4*>(basis);
    const float4* feat4  = reinterpret_cast<const float4*>(feat);
    const float4* w34    = reinterpret_cast<const float4*>(w3);

    for (int f = 0; f < FREQ; f++) {
        __syncthreads();   // protect previous iteration's LDS reads
        // ---- Stage A: basis slab -> LDS (1024 float4, 2 per thread) ----
        #pragma unroll
        for (int r = 0; r < 2; r++) {
            int i4  = t + 512 * r;       // 0..1023
            int ae  = i4 >> 6;           // edge 0..15
            int rem = i4 & 63;
            int aj  = rem >> 2;          // j 0..15
            int as4 = rem & 3;           // s-quad 0..3
            float4 v = basis4[(((size_t)(e0 + ae) * INDIM + aj) * FREQ + f) * 4 + as4];
            reinterpret_cast<float4*>(&basis_s[ae][aj][0])[as4] = v;
        }
        __syncthreads();
        // ---- Stage B: tmp[e][bci][bs] = sum_j feat[e][bci][j]*basis_s[e][j][bs] ----
        #pragma unroll 4
        for (int be = 0; be < 16; be++) {
            const float4* fg = feat4 + ((size_t)(e0 + be) * CIN + bci) * 4;
            float fr[16];
            #pragma unroll
            for (int i = 0; i < 4; i++) {
                float4 v = fg[i];
                fr[4*i+0] = v.x; fr[4*i+1] = v.y; fr[4*i+2] = v.z; fr[4*i+3] = v.w;
            }
            float a2 = 0.0f;
            #pragma unroll
            for (int j = 0; j < 16; j++) a2 += fr[j] * basis_s[be][j][bs];
            tmp_s[be][bci][bs] = a2;
        }
        __syncthreads();
        // ---- Stage C: radial on the fly + out accumulation ----
        #pragma unroll 2
        for (int ci = 0; ci < 32; ci++) {
            const float4* wr4 = w34 + ((size_t)co * KTOT + ci * FREQ + f) * 8;
            float wr[32];
            #pragma unroll
            for (int i = 0; i < 8; i++) {
                float4 v = wr4[i];
                wr[4*i+0] = v.x; wr[4*i+1] = v.y; wr[4*i+2] = v.z; wr[4*i+3] = v.w;
            }
            float rad = 0.0f;
            #pragma unroll
            for (int m = 0; m < 32; m++) rad += wr[m] * hreg[m];

            const float4* tp = reinterpret_cast<const float4*>(&tmp_s[ce][ci][0]);
            float4 t0 = tp[0], t1 = tp[1], t2 = tp[2], t3 = tp[3];
            acc[0]  += rad * t0.x;  acc[1]  += rad * t0.y;
            acc[2]  += rad * t0.z;  acc[3]  += rad * t0.w;
            acc[4]  += rad * t1.x;  acc[5]  += rad * t1.y;
            acc[6]  += rad * t1.z;  acc[7]  += rad * t1.w;
            acc[8]  += rad * t2.x;  acc[9]  += rad * t2.y;
            acc[10] += rad * t2.z;  acc[11] += rad * t2.w;
            acc[12] += rad * t3.x;  acc[13] += rad * t3.y;
            acc[14] += rad * t3.z;  acc[15] += rad * t3.w;
        }
    }

    // ---- epilogue: out[e0+ce][co][0..15] ----
    float4* og = reinterpret_cast<float4*>(out + (((size_t)(e0 + ce)) * COUT + co) * 16);
    og[0] = make_float4(acc[0],  acc[1],  acc[2],  acc[3]);
    og[1] = make_float4(acc[4],  acc[5],  acc[6],  acc[7]);
    og[2] = make_float4(acc[8],  acc[9],  acc[10], acc[11]);
    og[3] = make_float4(acc[12], acc[13], acc[14], acc[15]);
}

extern "C" void kernel_launch(void* const* d_in, const int* in_sizes, int n_in,
                              void* d_out, int out_size, void* d_ws, size_t ws_size,
                              hipStream_t stream) {
    const float* feat  = (const float*)d_in[0];
    const float* ef    = (const float*)d_in[1];
    const float* basis = (const float*)d_in[2];
    const float* w1    = (const float*)d_in[3];
    const float* b1    = (const float*)d_in[4];
    const float* g1    = (const float*)d_in[5];
    const float* be1   = (const float*)d_in[6];
    const float* w2    = (const float*)d_in[7];
    const float* b2    = (const float*)d_in[8];
    const float* g2    = (const float*)d_in[9];
    const float* be2   = (const float*)d_in[10];
    const float* w3    = (const float*)d_in[11];
    float* outp = (float*)d_out;
    float* h_ws = (float*)d_ws;   // [E,32] fp32 = 2 MB

    radial_h_kernel<<<NE / 8, 256, 0, stream>>>(ef, w1, b1, g1, be1, w2, b2, g2, be2, h_ws);
    conv_main<<<NE / 16, 512, 0, stream>>>(feat, basis, w3, h_ws, outp);
}